// Round 10
// baseline (271.654 us; speedup 1.0000x reference)
//
#include <hip/hip_runtime.h>
#include <math.h>

// Problem constants (fixed by the reference).
#define M_PTS 16384
#define N_PTS 16384

// Train grid: 42x42 row-major cells, h=0.25 over [-5.25,5.25).
// Cutoff: drop terms with exp2(arg) < 2^-TCUT <=> sq > TCUT/cmag = r_cut^2.
// ell=0.1 -> r_cut=0.527 -> K=3. Large ell -> windows grow to full grid
// naturally (no special fallback needed; item capacity covers worst case).
#define NC 42
#define NCELLS (NC * NC)          // 1764
#define NPAIR (NCELLS / 2)        // 882
#define H 0.25f
#define INV_H 4.0f
#define ORIG (-5.25f)
#define TCUT 20.0f

#define NTG 256                   // test groups of 64 (one wave each)
#define GROWS 42                  // max window rows (full grid worst case)
#define NPART 16                  // partial-histogram blocks
#define MAXITEMS 65536            // 256 groups * <=256 chunks
#define MAIN_BLOCKS 4096          // x4 waves = 16384 item slots

// ws byte offsets (no memsets needed: everything written before read)
#define OFF_PTR 0                                   // NPART*NCELLS ints
#define OFF_PTE (OFF_PTR + NPART * NCELLS * 4)
#define OFF_TRCUR (OFF_PTE + NPART * NCELLS * 4)
#define OFF_TECUR (OFF_TRCUR + NCELLS * 4)
#define OFF_NIT ((OFF_TECUR + NCELLS * 4 + 255) & ~255)
#define OFF_GOFF (OFF_NIT + 256)                    // NTG*GROWS ints
#define OFF_GPRE (OFF_GOFF + NTG * GROWS * 4)       // NTG*(GROWS+1) ints
#define OFF_ITEMS (OFF_GPRE + NTG * (GROWS + 1) * 4)
#define OFF_TRA ((OFF_ITEMS + MAXITEMS * 4 + 255) & ~255)  // float4[N]
#define OFF_TRW1 (OFF_TRA + N_PTS * 16)
#define OFF_T4 ((OFF_TRW1 + N_PTS * 4 + 255) & ~255)       // float4[M]
#define WS_NEED (OFF_T4 + (size_t)M_PTS * 16)       // ~1.2 MB

__device__ __forceinline__ float fexp2(float x) {
#if __has_builtin(__builtin_amdgcn_exp2f)
    return __builtin_amdgcn_exp2f(x);
#else
    return exp2f(x);
#endif
}

__device__ __forceinline__ void gatomic_fadd(float* p, float v) {
    asm volatile("global_atomic_add_f32 %0, %1, off" :: "v"(p), "v"(v) : "memory");
}

__device__ __forceinline__ int cellco(float v) {
    int c = (int)floorf((v - ORIG) * INV_H);
    return min(NC - 1, max(0, c));
}

// Banded test order: 4-row bands (last band 2 rows), column-major in band.
// Consecutive keys = spatially compact groups; bbox of a key range is
// closed-form (no Morton decode loops).
__device__ __forceinline__ int bkey(int cx, int cy) {
    int t = cy >> 2;
    int ht = (t == 10) ? 2 : 4;
    return t * 168 + cx * ht + (cy & 3);
}

// --- d1: partial histograms (LDS, no global zeroing) + zero out --------------
__global__ __launch_bounds__(1024) void histpart_kernel(
        const float2* __restrict__ Xtr, const float2* __restrict__ Xte,
        int* __restrict__ pTr, int* __restrict__ pTe,
        float2* __restrict__ out2) {
    __shared__ int hT[NCELLS], hE[NCELLS];
    const int tid = threadIdx.x, blk = blockIdx.x;
    for (int i = tid; i < NCELLS; i += 1024) { hT[i] = 0; hE[i] = 0; }
    __syncthreads();
    int i = blk * 1024 + tid;
    float2 t = Xtr[i];
    atomicAdd(&hT[cellco(t.y) * NC + cellco(t.x)], 1);
    float2 x = Xte[i];
    atomicAdd(&hE[bkey(cellco(x.x), cellco(x.y))], 1);
    out2[i] = make_float2(0.f, 0.f);
    __syncthreads();
    for (int c = tid; c < NCELLS; c += 1024) {
        pTr[blk * NCELLS + c] = hT[c];
        pTe[blk * NCELLS + c] = hE[c];
    }
}

// --- d2: sum partials + scans + per-group window planning + item list --------
__global__ __launch_bounds__(1024) void scanplan_kernel(
        const int* __restrict__ pTr, const int* __restrict__ pTe,
        const float* __restrict__ log_ell,
        int* __restrict__ trcur, int* __restrict__ tecur,
        int* __restrict__ gOff, int* __restrict__ gPre,
        int* __restrict__ items, int* __restrict__ nitG) {
    __shared__ int sc[1024];
    __shared__ int trsL[NCELLS + 1];
    __shared__ int tesL[NCELLS + 1];
    const int tid = threadIdx.x;
    if (tid == 0) nitG[0] = 0;

    // sum the 16 partials per cell
    __shared__ int hT[NCELLS], hE[NCELLS];
    for (int c = tid; c < NCELLS; c += 1024) {
        int sT = 0, sE = 0;
        for (int p = 0; p < NPART; ++p) {
            sT += pTr[p * NCELLS + c];
            sE += pTe[p * NCELLS + c];
        }
        hT[c] = sT; hE[c] = sE;
    }
    __syncthreads();

    // pairwise scan train counts
    int v0 = (tid < NPAIR) ? hT[2 * tid] : 0;
    int v1 = (tid < NPAIR) ? hT[2 * tid + 1] : 0;
    int v = v0 + v1;
    sc[tid] = v; __syncthreads();
    for (int o = 1; o < 1024; o <<= 1) {
        int u = (tid >= o) ? sc[tid - o] : 0;
        __syncthreads(); sc[tid] += u; __syncthreads();
    }
    if (tid < NPAIR) {
        int e = sc[tid] - v;
        trsL[2 * tid] = e;
        trsL[2 * tid + 1] = e + v0;
    }
    if (tid == NPAIR - 1) trsL[NCELLS] = sc[tid];
    __syncthreads();
    // pairwise scan test (banded) counts
    v0 = (tid < NPAIR) ? hE[2 * tid] : 0;
    v1 = (tid < NPAIR) ? hE[2 * tid + 1] : 0;
    v = v0 + v1;
    sc[tid] = v; __syncthreads();
    for (int o = 1; o < 1024; o <<= 1) {
        int u = (tid >= o) ? sc[tid - o] : 0;
        __syncthreads(); sc[tid] += u; __syncthreads();
    }
    if (tid < NPAIR) {
        int e = sc[tid] - v;
        tesL[2 * tid] = e;
        tesL[2 * tid + 1] = e + v0;
    }
    if (tid == NPAIR - 1) tesL[NCELLS] = sc[tid];
    __syncthreads();

    for (int c = tid; c < NCELLS; c += 1024) {
        trcur[c] = trsL[c];
        tecur[c] = tesL[c];
    }
    __syncthreads();

    // planner: one thread per group of 64 banded-sorted test points
    if (tid < NTG) {
        const int g = tid;
        const float ell = expf(log_ell[0]);
        const float cmag = 0.5f / (ell * ell) * 1.4426950408889634f;
        const float r2 = TCUT / cmag;
        const int K = (int)floorf(sqrtf(r2) * INV_H) + 1;

        // key range covered by this group's 64 sorted points
        int ka, kb;
        {
            int s = g * 64, lo = 0, hi = NCELLS;
            while (lo + 1 < hi) { int m = (lo + hi) >> 1; if (tesL[m] <= s) lo = m; else hi = m; }
            ka = lo;
            s = g * 64 + 63; lo = 0; hi = NCELLS;
            while (lo + 1 < hi) { int m = (lo + hi) >> 1; if (tesL[m] <= s) lo = m; else hi = m; }
            kb = lo;
        }
        // closed-form bbox of banded key range [ka, kb]
        int bx0, bx1, by0, by1;
        {
            int ta = ka / 168, tb = kb / 168;
            int hta = (ta == 10) ? 2 : 4;
            int ra = ka - ta * 168, rb = kb - tb * 168;
            int cxa = ra / hta;
            if (ta == tb) {
                int cxb = rb / hta;
                bx0 = cxa; bx1 = cxb;
                if (cxa == cxb) {
                    by0 = 4 * ta + (ra - cxa * hta);
                    by1 = 4 * ta + (rb - cxb * hta);
                } else {
                    by0 = 4 * ta;
                    by1 = min(NC - 1, 4 * ta + hta - 1);
                }
            } else {
                bx0 = 0; bx1 = NC - 1;
                int htb = (tb == 10) ? 2 : 4;
                by0 = 4 * ta;
                by1 = min(NC - 1, 4 * tb + htb - 1);
            }
        }

        const int ry0 = max(0, by0 - K), ry1 = min(NC - 1, by1 + K);
        int W = 0, idx = 0;
        gPre[g * (GROWS + 1)] = 0;
        for (int ry = ry0; ry <= ry1; ++ry, ++idx) {
            int dy = max(max(by0 - ry, ry - by1), 0);
            int kx;
            if (dy <= 1) kx = K;
            else {
                float d = (float)(dy - 1) * H;
                kx = (int)floorf(sqrtf(fmaxf(r2 - d * d, 0.f)) * INV_H) + 1;
            }
            int c0 = max(0, bx0 - kx);
            int c1 = min(NC - 1, bx1 + kx);
            int js = trsL[ry * NC + c0];
            int je = trsL[ry * NC + c1 + 1];
            gOff[g * GROWS + idx] = js - W;
            W += je - js;
            gPre[g * (GROWS + 1) + idx + 1] = W;
        }
        for (int i2 = idx; i2 < GROWS; ++i2)
            gPre[g * (GROWS + 1) + i2 + 1] = W;

        const int nch = (W + 63) >> 6;                  // <= 256
        int base = atomicAdd(nitG, nch);
        int r = 0;
        for (int k = 0; k < nch; ++k) {
            int start = k << 6;
            while (r < GROWS - 1 && start >= gPre[g * (GROWS + 1) + r + 1]) ++r;
            items[base + k] = g | (k << 8) | (r << 16);
        }
    }
}

// --- d3: scatter trains (row-major cells) and tests (banded order) -----------
// trA[p] = (-2c*t0, -2c*t1, c*|t|^2, sf2*a0), trW1[p] = sf2*a1.
// T4[p] = (x, y, c*|x|^2, orig idx bits).
__global__ __launch_bounds__(256) void scatter_kernel(
        const float2* __restrict__ Xtr, const float2* __restrict__ Xte,
        const float2* __restrict__ alpha, const float* __restrict__ log_ell,
        const float* __restrict__ log_sf,
        int* __restrict__ trcur, int* __restrict__ tecur,
        float4* __restrict__ trA, float* __restrict__ trW1,
        float4* __restrict__ T4) {
    const int bid = blockIdx.x;
    const float ell = expf(log_ell[0]);
    const float c = -0.5f / (ell * ell) * 1.4426950408889634f;  // c < 0
    if (bid < 64) {
        int i = bid * 256 + threadIdx.x;
        const float sf2 = expf(2.0f * log_sf[0]);
        float2 t = Xtr[i];
        float2 a = alpha[i];
        int ct = cellco(t.y) * NC + cellco(t.x);
        int pt = atomicAdd(&trcur[ct], 1);
        trA[pt] = make_float4(-2.f * c * t.x, -2.f * c * t.y,
                              c * (t.x * t.x + t.y * t.y), sf2 * a.x);
        trW1[pt] = sf2 * a.y;
    } else {
        int i = (bid - 64) * 256 + threadIdx.x;
        float2 x = Xte[i];
        int key = bkey(cellco(x.x), cellco(x.y));
        int px = atomicAdd(&tecur[key], 1);
        T4[px] = make_float4(x.x, x.y, c * (x.x * x.x + x.y * x.y),
                             __int_as_float(i));
    }
}

// --- d4: main kernel — equal-sized items, one wave each ----------------------
// Item = (group g, chunk k, start row r0). The wave stages 64 window trains
// to its private LDS slice (coalesced, row-table walk from r0), then runs the
// R2-proven broadcast loop: 16 iters x 4-train ILP, branch-free exp2 (pad
// slots underflow to 0). No __syncthreads (waves independent); atomic out.
__global__ __launch_bounds__(256, 8) void gp_item(
        const float4* __restrict__ T4, const float4* __restrict__ trA,
        const float* __restrict__ trW1, const int* __restrict__ gOff,
        const int* __restrict__ gPre, const int* __restrict__ items,
        const int* __restrict__ nitG, float* __restrict__ out) {
    __shared__ float4 sA[4][64];                       // 4 KB
    __shared__ __align__(16) float sW[4][64];          // 1 KB
    __shared__ int sPre[4][GROWS + 2];
    __shared__ int sOff[4][GROWS];

    const int wv = threadIdx.x >> 6;
    const int lane = threadIdx.x & 63;
    const int nit = nitG[0];

    for (int it = (blockIdx.x << 2) + wv; it < nit; it += MAIN_BLOCKS * 4) {
        const int item = items[it];
        const int g = item & 0xFF;
        const int k = (item >> 8) & 0xFF;
        const int r0 = (item >> 16) & 0x3F;

        if (lane < GROWS) sOff[wv][lane] = gOff[g * GROWS + lane];
        if (lane < GROWS + 1) sPre[wv][lane] = gPre[g * (GROWS + 1) + lane];
        float4 tp = T4[(g << 6) + lane];
        __builtin_amdgcn_wave_barrier();
        asm volatile("" ::: "memory");

        const int W = sPre[wv][GROWS];
        const int gg = (k << 6) + lane;
        float4 tv; float wvv;
        if (gg < W) {
            int r = r0;
            while (r < GROWS - 1 && gg >= sPre[wv][r + 1]) ++r;
            int j = gg + sOff[wv][r];
            tv = trA[j];                  // coalesced 16B/lane
            wvv = trW1[j];
        } else {
            tv = make_float4(0.f, 0.f, -1.0e30f, 0.f);  // exp2 -> 0, weight 0
            wvv = 0.f;
        }
        sA[wv][lane] = tv;
        sW[wv][lane] = wvv;
        __builtin_amdgcn_wave_barrier();
        asm volatile("" ::: "memory");

        const float x = tp.x, y = tp.y, b = tp.z;
        const int oi = __float_as_int(tp.w);
        float a0 = 0.f, a1 = 0.f;
#pragma unroll 4
        for (int q = 0; q < 16; ++q) {
            float4 t0 = sA[wv][4 * q];
            float4 t1 = sA[wv][4 * q + 1];
            float4 t2 = sA[wv][4 * q + 2];
            float4 t3 = sA[wv][4 * q + 3];
            float4 w4 = *(const float4*)&sW[wv][4 * q];
            float e0 = fexp2(fmaf(t0.x, x, fmaf(t0.y, y, b + t0.z)));
            float e1 = fexp2(fmaf(t1.x, x, fmaf(t1.y, y, b + t1.z)));
            float e2 = fexp2(fmaf(t2.x, x, fmaf(t2.y, y, b + t2.z)));
            float e3 = fexp2(fmaf(t3.x, x, fmaf(t3.y, y, b + t3.z)));
            a0 = fmaf(e0, t0.w, a0); a1 = fmaf(e0, w4.x, a1);
            a0 = fmaf(e1, t1.w, a0); a1 = fmaf(e1, w4.y, a1);
            a0 = fmaf(e2, t2.w, a0); a1 = fmaf(e2, w4.z, a1);
            a0 = fmaf(e3, t3.w, a0); a1 = fmaf(e3, w4.w, a1);
        }
        gatomic_fadd(&out[2 * oi], a0);
        gatomic_fadd(&out[2 * oi + 1], a1);
        __builtin_amdgcn_wave_barrier();
        asm volatile("" ::: "memory");
    }
}

// --- dense fallback (ws too small) ------------------------------------------
__global__ __launch_bounds__(256, 8) void gp_dense(
        const float2* __restrict__ Xte, const float2* __restrict__ Xtr,
        const float2* __restrict__ alpha, const float* __restrict__ log_ell,
        const float* __restrict__ log_sf, float* __restrict__ out) {
    __shared__ float4 sSt[128];
    __shared__ float sA1[128];
    const int tid = threadIdx.x;
    const float ell = expf(log_ell[0]);
    const float c = -0.5f / (ell * ell) * 1.4426950408889634f;
    const int j0 = blockIdx.y * 128;
    if (tid < 128) {
        const float sf2 = expf(2.0f * log_sf[0]);
        float2 t = Xtr[j0 + tid];
        float2 a = alpha[j0 + tid];
        sSt[tid] = make_float4(-2.f * c * t.x, -2.f * c * t.y,
                               c * (t.x * t.x + t.y * t.y), sf2 * a.x);
        sA1[tid] = sf2 * a.y;
    }
    const int base = blockIdx.x * 1024 + tid;
    float2 x0 = Xte[base], x1 = Xte[base + 256];
    float2 x2 = Xte[base + 512], x3 = Xte[base + 768];
    const float b0 = c * (x0.x * x0.x + x0.y * x0.y);
    const float b1 = c * (x1.x * x1.x + x1.y * x1.y);
    const float b2 = c * (x2.x * x2.x + x2.y * x2.y);
    const float b3 = c * (x3.x * x3.x + x3.y * x3.y);
    __syncthreads();
    float a00 = 0.f, a01 = 0.f, a10 = 0.f, a11 = 0.f;
    float a20 = 0.f, a21 = 0.f, a30 = 0.f, a31 = 0.f;
#pragma unroll 2
    for (int j = 0; j < 128; ++j) {
        float4 s = sSt[j];
        float w1 = sA1[j];
        float e0 = fexp2(fminf(fmaf(s.x, x0.x, fmaf(s.y, x0.y, b0 + s.z)), 0.f));
        float e1 = fexp2(fminf(fmaf(s.x, x1.x, fmaf(s.y, x1.y, b1 + s.z)), 0.f));
        float e2 = fexp2(fminf(fmaf(s.x, x2.x, fmaf(s.y, x2.y, b2 + s.z)), 0.f));
        float e3 = fexp2(fminf(fmaf(s.x, x3.x, fmaf(s.y, x3.y, b3 + s.z)), 0.f));
        a00 = fmaf(e0, s.w, a00); a01 = fmaf(e0, w1, a01);
        a10 = fmaf(e1, s.w, a10); a11 = fmaf(e1, w1, a11);
        a20 = fmaf(e2, s.w, a20); a21 = fmaf(e2, w1, a21);
        a30 = fmaf(e3, s.w, a30); a31 = fmaf(e3, w1, a31);
    }
    gatomic_fadd(&out[2 * base], a00);            gatomic_fadd(&out[2 * base + 1], a01);
    gatomic_fadd(&out[2 * (base + 256)], a10);    gatomic_fadd(&out[2 * (base + 256) + 1], a11);
    gatomic_fadd(&out[2 * (base + 512)], a20);    gatomic_fadd(&out[2 * (base + 512) + 1], a21);
    gatomic_fadd(&out[2 * (base + 768)], a30);    gatomic_fadd(&out[2 * (base + 768) + 1], a31);
}

extern "C" void kernel_launch(void* const* d_in, const int* in_sizes, int n_in,
                              void* d_out, int out_size, void* d_ws, size_t ws_size,
                              hipStream_t stream) {
    const float2* Xte = (const float2*)d_in[0];
    const float2* Xtr = (const float2*)d_in[1];
    const float2* alpha = (const float2*)d_in[2];
    const float* log_ell = (const float*)d_in[3];
    const float* log_sf = (const float*)d_in[4];
    float* out = (float*)d_out;

    if (ws_size >= WS_NEED) {
        char* ws = (char*)d_ws;
        int* pTr = (int*)(ws + OFF_PTR);
        int* pTe = (int*)(ws + OFF_PTE);
        int* trcur = (int*)(ws + OFF_TRCUR);
        int* tecur = (int*)(ws + OFF_TECUR);
        int* nitG = (int*)(ws + OFF_NIT);
        int* gOff = (int*)(ws + OFF_GOFF);
        int* gPre = (int*)(ws + OFF_GPRE);
        int* items = (int*)(ws + OFF_ITEMS);
        float4* trA = (float4*)(ws + OFF_TRA);
        float* trW1 = (float*)(ws + OFF_TRW1);
        float4* T4 = (float4*)(ws + OFF_T4);

        histpart_kernel<<<NPART, 1024, 0, stream>>>(Xtr, Xte, pTr, pTe,
                                                    (float2*)out);
        scanplan_kernel<<<1, 1024, 0, stream>>>(pTr, pTe, log_ell, trcur, tecur,
                                                gOff, gPre, items, nitG);
        scatter_kernel<<<128, 256, 0, stream>>>(Xtr, Xte, alpha, log_ell, log_sf,
                                                trcur, tecur, trA, trW1, T4);
        gp_item<<<MAIN_BLOCKS, 256, 0, stream>>>(T4, trA, trW1, gOff, gPre,
                                                 items, nitG, out);
    } else {
        hipMemsetAsync(out, 0, (size_t)out_size * sizeof(float), stream);
        dim3 grid(M_PTS / 1024, N_PTS / 128);
        gp_dense<<<grid, 256, 0, stream>>>(Xte, Xtr, alpha, log_ell, log_sf, out);
    }
}

// Round 11
// 138.708 us; speedup vs baseline: 1.9585x; 1.9585x over previous
//
#include <hip/hip_runtime.h>
#include <math.h>

// Problem constants (fixed by the reference).
#define M_PTS 16384
#define N_PTS 16384

// Train grid: 42x42 row-major cells, h=0.25 over [-5.25,5.25).
// Drop terms with exp2(arg) < 2^-TCUT <=> sq > TCUT/cmag = r_cut^2.
// ell=0.1 -> r_cut=0.527 -> K=3. Large ell -> windows grow to the full grid
// naturally (correct, just slower).
#define NC 42
#define NCELLS (NC * NC)          // 1764
#define NPAIR (NCELLS / 2)        // 882
#define H 0.25f
#define INV_H 4.0f
#define ORIG (-5.25f)
#define TCUT 20.0f

#define NTB 64                    // test blocks of 256 banded-sorted points
#define NPART 16                  // partial-histogram blocks
#define SPAN 256                  // max trains per item (contiguous!)
#define MAXITEMS 8192             // bound: sum(W_b/256 + 42) <= 64*106 = 6784
#define MAIN_BLOCKS 1024

// ws byte offsets (everything written before read; no memsets)
#define OFF_PTR 0                                   // NPART*NCELLS ints
#define OFF_PTE (OFF_PTR + NPART * NCELLS * 4)
#define OFF_TRCUR (OFF_PTE + NPART * NCELLS * 4)
#define OFF_TECUR (OFF_TRCUR + NCELLS * 4)
#define OFF_NIT ((OFF_TECUR + NCELLS * 4 + 255) & ~255)
#define OFF_ITEMS (OFF_NIT + 256)
#define OFF_TRA ((OFF_ITEMS + MAXITEMS * 4 + 255) & ~255)  // float4[N]
#define OFF_TRW1 (OFF_TRA + N_PTS * 16)
#define OFF_T4 ((OFF_TRW1 + N_PTS * 4 + 255) & ~255)       // float4[M]
#define WS_NEED (OFF_T4 + (size_t)M_PTS * 16)       // ~900 KB

__device__ __forceinline__ float fexp2(float x) {
#if __has_builtin(__builtin_amdgcn_exp2f)
    return __builtin_amdgcn_exp2f(x);
#else
    return exp2f(x);
#endif
}

__device__ __forceinline__ void gatomic_fadd(float* p, float v) {
    asm volatile("global_atomic_add_f32 %0, %1, off" :: "v"(p), "v"(v) : "memory");
}

__device__ __forceinline__ int cellco(float v) {
    int c = (int)floorf((v - ORIG) * INV_H);
    return min(NC - 1, max(0, c));
}

// Banded test key: 4-row bands (last band 2 rows), column-major within band.
// Consecutive keys = spatially square-ish groups -> tight bboxes.
__device__ __forceinline__ int bkey(int cx, int cy) {
    int t = cy >> 2;
    int ht = (t == 10) ? 2 : 4;
    return t * 168 + cx * ht + (cy - 4 * t);
}

// --- d1: partial histograms (LDS, no global zeroing) + zero out --------------
__global__ __launch_bounds__(1024) void histpart_kernel(
        const float2* __restrict__ Xtr, const float2* __restrict__ Xte,
        int* __restrict__ pTr, int* __restrict__ pTe,
        float2* __restrict__ out2) {
    __shared__ int hT[NCELLS], hE[NCELLS];
    const int tid = threadIdx.x, blk = blockIdx.x;
    for (int i = tid; i < NCELLS; i += 1024) { hT[i] = 0; hE[i] = 0; }
    __syncthreads();
    int i = blk * 1024 + tid;
    float2 t = Xtr[i];
    atomicAdd(&hT[cellco(t.y) * NC + cellco(t.x)], 1);
    float2 x = Xte[i];
    atomicAdd(&hE[bkey(cellco(x.x), cellco(x.y))], 1);
    out2[i] = make_float2(0.f, 0.f);
    __syncthreads();
    for (int c = tid; c < NCELLS; c += 1024) {
        pTr[blk * NCELLS + c] = hT[c];
        pTe[blk * NCELLS + c] = hE[c];
    }
}

// --- d2: sum partials + scans + per-test-block planning + item list ----------
// Items are CONTIGUOUS train spans (split at row boundaries, <= SPAN each):
// item = start(14b) | (len-1)(8b)<<14 | b(6b)<<22.
__global__ __launch_bounds__(1024) void scanplan_kernel(
        const int* __restrict__ pTr, const int* __restrict__ pTe,
        const float* __restrict__ log_ell,
        int* __restrict__ trcur, int* __restrict__ tecur,
        int* __restrict__ items, int* __restrict__ nitG) {
    __shared__ int sc[1024];
    __shared__ int trsL[NCELLS + 1];
    __shared__ int tesL[NCELLS + 1];
    __shared__ int hT[NCELLS], hE[NCELLS];
    const int tid = threadIdx.x;
    if (tid == 0) nitG[0] = 0;

    for (int c = tid; c < NCELLS; c += 1024) {
        int sT = 0, sE = 0;
        for (int p = 0; p < NPART; ++p) {
            sT += pTr[p * NCELLS + c];
            sE += pTe[p * NCELLS + c];
        }
        hT[c] = sT; hE[c] = sE;
    }
    __syncthreads();

    // pairwise scan of train counts (row-major cells)
    int v0 = (tid < NPAIR) ? hT[2 * tid] : 0;
    int v1 = (tid < NPAIR) ? hT[2 * tid + 1] : 0;
    int v = v0 + v1;
    sc[tid] = v; __syncthreads();
    for (int o = 1; o < 1024; o <<= 1) {
        int u = (tid >= o) ? sc[tid - o] : 0;
        __syncthreads(); sc[tid] += u; __syncthreads();
    }
    if (tid < NPAIR) {
        int e = sc[tid] - v;
        trsL[2 * tid] = e;
        trsL[2 * tid + 1] = e + v0;
    }
    if (tid == NPAIR - 1) trsL[NCELLS] = sc[tid];
    __syncthreads();
    // pairwise scan of test counts (banded keys)
    v0 = (tid < NPAIR) ? hE[2 * tid] : 0;
    v1 = (tid < NPAIR) ? hE[2 * tid + 1] : 0;
    v = v0 + v1;
    sc[tid] = v; __syncthreads();
    for (int o = 1; o < 1024; o <<= 1) {
        int u = (tid >= o) ? sc[tid - o] : 0;
        __syncthreads(); sc[tid] += u; __syncthreads();
    }
    if (tid < NPAIR) {
        int e = sc[tid] - v;
        tesL[2 * tid] = e;
        tesL[2 * tid + 1] = e + v0;
    }
    if (tid == NPAIR - 1) tesL[NCELLS] = sc[tid];
    __syncthreads();

    for (int c = tid; c < NCELLS; c += 1024) {
        trcur[c] = trsL[c];
        tecur[c] = tesL[c];
    }
    __syncthreads();

    // planner: one thread per test block of 256 banded-sorted points
    if (tid < NTB) {
        const int g = tid;
        const float ell = expf(log_ell[0]);
        const float cmag = 0.5f / (ell * ell) * 1.4426950408889634f;
        const float r2 = TCUT / cmag;
        float kf = sqrtf(r2) * INV_H;
        const int K = (kf >= (float)NC) ? NC : ((int)kf + 1);

        // key range of this block's 256 sorted points
        int ka, kb;
        {
            int s = g * 256, lo = 0, hi = NCELLS;
            while (lo + 1 < hi) { int m = (lo + hi) >> 1; if (tesL[m] <= s) lo = m; else hi = m; }
            ka = lo;
            s = g * 256 + 255; lo = 0; hi = NCELLS;
            while (lo + 1 < hi) { int m = (lo + hi) >> 1; if (tesL[m] <= s) lo = m; else hi = m; }
            kb = lo;
        }
        // closed-form bbox of banded key range [ka,kb]
        int bx0, bx1, by0, by1;
        {
            int ta = ka / 168, tb = kb / 168;
            int hta = (ta == 10) ? 2 : 4;
            int ra = ka - ta * 168;
            if (ta == tb) {
                int rb = kb - ta * 168;
                int cxa = ra / hta, cxb = rb / hta;
                bx0 = cxa; bx1 = cxb;
                if (cxa == cxb) {
                    by0 = 4 * ta + (ra - cxa * hta);
                    by1 = 4 * ta + (rb - cxb * hta);
                } else {
                    by0 = 4 * ta;
                    by1 = min(NC - 1, 4 * ta + hta - 1);
                }
            } else {
                int htb = (tb == 10) ? 2 : 4;
                bx0 = 0; bx1 = NC - 1;
                by0 = 4 * ta;
                by1 = min(NC - 1, 4 * tb + htb - 1);
            }
        }

        const int ry0 = max(0, by0 - K), ry1 = min(NC - 1, by1 + K);
        // pass 1: count spans
        int ns = 0;
        for (int ry = ry0; ry <= ry1; ++ry) {
            int dy = max(max(by0 - ry, ry - by1), 0);
            int kx;
            if (dy <= 1) kx = K;
            else {
                float d = (float)(dy - 1) * H;
                float vq = r2 - d * d;
                float kq = (vq > 0.f) ? sqrtf(vq) * INV_H : 0.f;
                kx = (kq >= (float)NC) ? NC : ((int)kq + 1);
            }
            int c0 = max(0, bx0 - kx), c1 = min(NC - 1, bx1 + kx);
            int js = trsL[ry * NC + c0], je = trsL[ry * NC + c1 + 1];
            if (je > js) ns += (je - js + SPAN - 1) / SPAN;
        }
        int slot = atomicAdd(nitG, ns);
        // pass 2: emit
        for (int ry = ry0; ry <= ry1; ++ry) {
            int dy = max(max(by0 - ry, ry - by1), 0);
            int kx;
            if (dy <= 1) kx = K;
            else {
                float d = (float)(dy - 1) * H;
                float vq = r2 - d * d;
                float kq = (vq > 0.f) ? sqrtf(vq) * INV_H : 0.f;
                kx = (kq >= (float)NC) ? NC : ((int)kq + 1);
            }
            int c0 = max(0, bx0 - kx), c1 = min(NC - 1, bx1 + kx);
            int js = trsL[ry * NC + c0], je = trsL[ry * NC + c1 + 1];
            for (int s = js; s < je; s += SPAN) {
                int len = min(SPAN, je - s);
                items[slot++] = s | ((len - 1) << 14) | (g << 22);
            }
        }
    }
}

// --- d3: scatter trains (row-major cells) and tests (banded order) -----------
// trA[p] = (-2c*t0, -2c*t1, c*|t|^2, sf2*a0), trW1[p] = sf2*a1.
// T4[p] = (x, y, c*|x|^2, orig idx bits).
__global__ __launch_bounds__(256) void scatter_kernel(
        const float2* __restrict__ Xtr, const float2* __restrict__ Xte,
        const float2* __restrict__ alpha, const float* __restrict__ log_ell,
        const float* __restrict__ log_sf,
        int* __restrict__ trcur, int* __restrict__ tecur,
        float4* __restrict__ trA, float* __restrict__ trW1,
        float4* __restrict__ T4) {
    const int bid = blockIdx.x;
    const float ell = expf(log_ell[0]);
    const float c = -0.5f / (ell * ell) * 1.4426950408889634f;  // c < 0
    if (bid < 64) {
        int i = bid * 256 + threadIdx.x;
        const float sf2 = expf(2.0f * log_sf[0]);
        float2 t = Xtr[i];
        float2 a = alpha[i];
        int ct = cellco(t.y) * NC + cellco(t.x);
        int pt = atomicAdd(&trcur[ct], 1);
        trA[pt] = make_float4(-2.f * c * t.x, -2.f * c * t.y,
                              c * (t.x * t.x + t.y * t.y), sf2 * a.x);
        trW1[pt] = sf2 * a.y;
    } else {
        int i = (bid - 64) * 256 + threadIdx.x;
        float2 x = Xte[i];
        int key = bkey(cellco(x.x), cellco(x.y));
        int px = atomicAdd(&tecur[key], 1);
        T4[px] = make_float4(x.x, x.y, c * (x.x * x.x + x.y * x.y),
                             __int_as_float(i));
    }
}

// --- d4: main kernel — fat contiguous-span items -----------------------------
// Item = (test block b: 256 points, contiguous train span [start, start+len)).
// Block: stage span to LDS (1 coalesced 16B+4B load/thread, NO row walk),
// then each of 4 waves runs the R2-proven broadcast loop for its own 64 test
// points (1 test/thread): 4-train ILP, branch-free exp2 (pads underflow to 0).
// Each thread owns a distinct test point -> 2 atomics/thread, skipped if zero.
__global__ __launch_bounds__(256) void gp_span(
        const float4* __restrict__ T4, const float4* __restrict__ trA,
        const float* __restrict__ trW1, const int* __restrict__ items,
        const int* __restrict__ nitG, float* __restrict__ out) {
    __shared__ float4 sA[SPAN];                      // 4 KB
    __shared__ __align__(16) float sW[SPAN];         // 1 KB

    const int tid = threadIdx.x;
    const int nit = nitG[0];

    for (int it = blockIdx.x; it < nit; it += MAIN_BLOCKS) {
        const int item = items[it];
        const int start = item & 0x3FFF;
        const int len = ((item >> 14) & 0xFF) + 1;
        const int b = item >> 22;

        float4 tp = T4[(b << 8) + tid];              // this thread's test point
        const int lenp = (len + 3) & ~3;
        if (tid < len) {
            sA[tid] = trA[start + tid];              // contiguous, coalesced
            sW[tid] = trW1[start + tid];
        } else if (tid < lenp) {
            sA[tid] = make_float4(0.f, 0.f, -1.0e30f, 0.f);  // exp2 -> 0
            sW[tid] = 0.f;
        }
        __syncthreads();

        const float x = tp.x, y = tp.y, bq = tp.z;
        const int oi = __float_as_int(tp.w);
        float a0 = 0.f, a1 = 0.f;
        const int nq = lenp >> 2;
#pragma unroll 2
        for (int q = 0; q < nq; ++q) {
            float4 t0 = sA[4 * q];
            float4 t1 = sA[4 * q + 1];
            float4 t2 = sA[4 * q + 2];
            float4 t3 = sA[4 * q + 3];
            float4 w4 = *(const float4*)&sW[4 * q];
            float e0 = fexp2(fmaf(t0.x, x, fmaf(t0.y, y, bq + t0.z)));
            float e1 = fexp2(fmaf(t1.x, x, fmaf(t1.y, y, bq + t1.z)));
            float e2 = fexp2(fmaf(t2.x, x, fmaf(t2.y, y, bq + t2.z)));
            float e3 = fexp2(fmaf(t3.x, x, fmaf(t3.y, y, bq + t3.z)));
            a0 = fmaf(e0, t0.w, a0); a1 = fmaf(e0, w4.x, a1);
            a0 = fmaf(e1, t1.w, a0); a1 = fmaf(e1, w4.y, a1);
            a0 = fmaf(e2, t2.w, a0); a1 = fmaf(e2, w4.z, a1);
            a0 = fmaf(e3, t3.w, a0); a1 = fmaf(e3, w4.w, a1);
        }
        if (a0 != 0.f || a1 != 0.f) {
            gatomic_fadd(&out[2 * oi], a0);
            gatomic_fadd(&out[2 * oi + 1], a1);
        }
        __syncthreads();                             // LDS reuse by next item
    }
}

// --- dense fallback (ws too small) ------------------------------------------
__global__ __launch_bounds__(256, 8) void gp_dense(
        const float2* __restrict__ Xte, const float2* __restrict__ Xtr,
        const float2* __restrict__ alpha, const float* __restrict__ log_ell,
        const float* __restrict__ log_sf, float* __restrict__ out) {
    __shared__ float4 sSt[128];
    __shared__ float sA1[128];
    const int tid = threadIdx.x;
    const float ell = expf(log_ell[0]);
    const float c = -0.5f / (ell * ell) * 1.4426950408889634f;
    const int j0 = blockIdx.y * 128;
    if (tid < 128) {
        const float sf2 = expf(2.0f * log_sf[0]);
        float2 t = Xtr[j0 + tid];
        float2 a = alpha[j0 + tid];
        sSt[tid] = make_float4(-2.f * c * t.x, -2.f * c * t.y,
                               c * (t.x * t.x + t.y * t.y), sf2 * a.x);
        sA1[tid] = sf2 * a.y;
    }
    const int base = blockIdx.x * 1024 + tid;
    float2 x0 = Xte[base], x1 = Xte[base + 256];
    float2 x2 = Xte[base + 512], x3 = Xte[base + 768];
    const float b0 = c * (x0.x * x0.x + x0.y * x0.y);
    const float b1 = c * (x1.x * x1.x + x1.y * x1.y);
    const float b2 = c * (x2.x * x2.x + x2.y * x2.y);
    const float b3 = c * (x3.x * x3.x + x3.y * x3.y);
    __syncthreads();
    float a00 = 0.f, a01 = 0.f, a10 = 0.f, a11 = 0.f;
    float a20 = 0.f, a21 = 0.f, a30 = 0.f, a31 = 0.f;
#pragma unroll 2
    for (int j = 0; j < 128; ++j) {
        float4 s = sSt[j];
        float w1 = sA1[j];
        float e0 = fexp2(fminf(fmaf(s.x, x0.x, fmaf(s.y, x0.y, b0 + s.z)), 0.f));
        float e1 = fexp2(fminf(fmaf(s.x, x1.x, fmaf(s.y, x1.y, b1 + s.z)), 0.f));
        float e2 = fexp2(fminf(fmaf(s.x, x2.x, fmaf(s.y, x2.y, b2 + s.z)), 0.f));
        float e3 = fexp2(fminf(fmaf(s.x, x3.x, fmaf(s.y, x3.y, b3 + s.z)), 0.f));
        a00 = fmaf(e0, s.w, a00); a01 = fmaf(e0, w1, a01);
        a10 = fmaf(e1, s.w, a10); a11 = fmaf(e1, w1, a11);
        a20 = fmaf(e2, s.w, a20); a21 = fmaf(e2, w1, a21);
        a30 = fmaf(e3, s.w, a30); a31 = fmaf(e3, w1, a31);
    }
    gatomic_fadd(&out[2 * base], a00);            gatomic_fadd(&out[2 * base + 1], a01);
    gatomic_fadd(&out[2 * (base + 256)], a10);    gatomic_fadd(&out[2 * (base + 256) + 1], a11);
    gatomic_fadd(&out[2 * (base + 512)], a20);    gatomic_fadd(&out[2 * (base + 512) + 1], a21);
    gatomic_fadd(&out[2 * (base + 768)], a30);    gatomic_fadd(&out[2 * (base + 768) + 1], a31);
}

extern "C" void kernel_launch(void* const* d_in, const int* in_sizes, int n_in,
                              void* d_out, int out_size, void* d_ws, size_t ws_size,
                              hipStream_t stream) {
    const float2* Xte = (const float2*)d_in[0];
    const float2* Xtr = (const float2*)d_in[1];
    const float2* alpha = (const float2*)d_in[2];
    const float* log_ell = (const float*)d_in[3];
    const float* log_sf = (const float*)d_in[4];
    float* out = (float*)d_out;

    if (ws_size >= WS_NEED) {
        char* ws = (char*)d_ws;
        int* pTr = (int*)(ws + OFF_PTR);
        int* pTe = (int*)(ws + OFF_PTE);
        int* trcur = (int*)(ws + OFF_TRCUR);
        int* tecur = (int*)(ws + OFF_TECUR);
        int* nitG = (int*)(ws + OFF_NIT);
        int* items = (int*)(ws + OFF_ITEMS);
        float4* trA = (float4*)(ws + OFF_TRA);
        float* trW1 = (float*)(ws + OFF_TRW1);
        float4* T4 = (float4*)(ws + OFF_T4);

        histpart_kernel<<<NPART, 1024, 0, stream>>>(Xtr, Xte, pTr, pTe,
                                                    (float2*)out);
        scanplan_kernel<<<1, 1024, 0, stream>>>(pTr, pTe, log_ell, trcur, tecur,
                                                items, nitG);
        scatter_kernel<<<128, 256, 0, stream>>>(Xtr, Xte, alpha, log_ell, log_sf,
                                                trcur, tecur, trA, trW1, T4);
        gp_span<<<MAIN_BLOCKS, 256, 0, stream>>>(T4, trA, trW1, items, nitG, out);
    } else {
        hipMemsetAsync(out, 0, (size_t)out_size * sizeof(float), stream);
        dim3 grid(M_PTS / 1024, N_PTS / 128);
        gp_dense<<<grid, 256, 0, stream>>>(Xte, Xtr, alpha, log_ell, log_sf, out);
    }
}